// Round 7
// baseline (247.458 us; speedup 1.0000x reference)
//
#include <hip/hip_runtime.h>

// MakeCutouts: 32 cutouts of (8,3,512,512) fp32 -> adaptive avg pool 224x224.
//
// R10: R8/R9 showed barriers + block granularity are the binder (all pipes
// <30% busy; max pipe floor ~30us vs ~60us achieved). The stage->pool dep is
// only ROW-wide, so make each WAVE fully autonomous: wave owns output rows
// end-to-end with a private LDS slice (no cross-wave sharing, NO s_barrier
// in the entire kernel). Per row: load wp input rows (2 f32x4/lane) -> reduce
// in regs (v_pk_add_f32) -> ds_write own slice -> pool (lane computes q =
// lane+64m, cndmask-select window, so out-of-window garbage is discarded) ->
// coalesced row store. Next row's global loads issue during pool; all
// ordering is intra-wave waitcnts the compiler inserts.
// Grid 10752 = 8*1344 (bijective XCD chunk: XCD k owns planes [3k,3k+3),
// 1MB plane hot in private L2 -> FETCH stays ~19MB). 16 rows/block = 4/wave,
// 42 self-balancing rounds/CU. LDS 4 waves x 2 bufs x 520 f = 16.6 KB and
// launch_bounds(256,8) -> 8 blocks/CU = 32 waves. Plain stores (R9's
// nontemporal inflated WRITE 150->166MB).

typedef float f32x4 __attribute__((ext_vector_type(4)));

constexpr int OUTSZ = 224;
constexpr int BB    = 8;
constexpr int CC    = 3;
constexpr int HH    = 512;
constexpr int WW    = 512;
constexpr int CUTN  = 32;

constexpr int RPB    = 16;             // output rows per block
constexpr int RPW    = 4;              // rows per wave
constexpr int NCH    = OUTSZ / RPB;    // 14 chunks per (plane,cutout)
constexpr int SLICEF = WW + 8;         // 520 floats per buffer (pad for sel reads)
constexpr int NPLANE = BB * CC;                    // 24
constexpr int NBLOCKS = NPLANE * CUTN * NCH;       // 10752 = 8 * 1344
constexpr int NXCD   = 8;
constexpr int CHUNKSZ = NBLOCKS / NXCD;            // 1344 = 3 planes worth

// Issue global loads for output row p into regs. p is wave-uniform (derived
// from readfirstlane'd wave id + literal) -> rs/wp/row-base on SALU, loads
// under uniform s_cbranch. Unloaded v[m] are stale but never consumed.
__device__ __forceinline__ void load_row(const float* __restrict__ plane_p,
                                         int S, int p, int lane, f32x4 (&v)[8])
{
    int rs = (p * S) / OUTSZ;                          // scalar magic div
    int wp = ((p + 1) * S + OUTSZ - 1) / OUTSZ - rs;   // 1..4, scalar
    const f32x4* rp = (const f32x4*)(plane_p + (size_t)rs * WW);
    int c0 = lane;                    // cols [4*lane, 4*lane+4)
    int c1 = lane + 64;               // cols [256+4*lane, ...)
    v[0] = rp[c0];        v[1] = rp[c1];
    if (wp > 1) { v[2] = rp[c0 + 128]; v[3] = rp[c1 + 128]; }
    if (wp > 2) { v[4] = rp[c0 + 256]; v[5] = rp[c1 + 256]; }
    if (wp > 3) { v[6] = rp[c0 + 384]; v[7] = rp[c1 + 384]; }
}

// Reduce prefetched rows (v_pk_add_f32), scale by 1/wp, write the 512-wide
// averaged row into this wave's slice (2x ds_write_b128 per lane).
__device__ __forceinline__ void reduce_write(float* __restrict__ buf,
                                             int S, int p, int lane,
                                             f32x4 (&v)[8])
{
    int rs = (p * S) / OUTSZ;
    int wp = ((p + 1) * S + OUTSZ - 1) / OUTSZ - rs;   // 1..4, scalar
    f32x4 a0 = v[0], a1 = v[1];
    if (wp > 1) { a0 += v[2]; a1 += v[3]; }
    if (wp > 2) { a0 += v[4]; a1 += v[5]; }
    if (wp > 3) { a0 += v[6]; a1 += v[7]; }
    float iv = (wp == 1) ? 1.0f : (wp == 2) ? 0.5f
             : (wp == 3) ? (1.0f / 3.0f) : 0.25f;      // scalar cselect
    a0 *= iv; a1 *= iv;
    f32x4* t4 = (f32x4*)buf;
    t4[lane] = a0;
    t4[lane + 64] = a1;
}

// Pool one averaged row: lane handles q = lane + 64m (m=3 only for lane<32).
// cndmask-select window: out-of-window reads are discarded, so stale/pad
// data is harmless (reads stay inside the 520-float slice).
template <int WIN>
__device__ __forceinline__ void pool_row(const float* __restrict__ buf,
                                         float* __restrict__ outrow,
                                         int x0, int lane,
                                         const int* __restrict__ sqv,
                                         const int* __restrict__ wqv,
                                         const float* __restrict__ invqv)
{
#pragma unroll
    for (int m = 0; m < 4; ++m) {
        if (m == 3 && lane >= 32) break;       // q >= 224
        const float* tr = buf + x0 + sqv[m];
        float z = 0.0f;
        float s = tr[0];                        // adjacent -> ds_read2_b32
        s += (wqv[m] > 1) ? tr[1] : z;
        s += (wqv[m] > 2) ? tr[2] : z;
        if (WIN == 4) s += (wqv[m] > 3) ? tr[3] : z;
        outrow[lane + 64 * m] = s * invqv[m];   // wave store: 224 contiguous
    }
}

template <int WIN>
__device__ __forceinline__ void run_rows(const float* __restrict__ plane_p,
                                         float* __restrict__ s0,
                                         float* __restrict__ s1,
                                         float* __restrict__ outbase,
                                         int S, int x0, int p0, int lane,
                                         const int* __restrict__ sqv,
                                         const int* __restrict__ wqv,
                                         const float* __restrict__ invqv)
{
    f32x4 v[8];
    load_row(plane_p, S, p0, lane, v);          // prologue: row 0 in flight
#pragma unroll
    for (int r = 0; r < RPW; ++r) {
        float* buf = (r & 1) ? s1 : s0;         // static after unroll
        reduce_write(buf, S, p0 + r, lane, v);  // waits vmcnt via reg dep
        if (r + 1 < RPW)
            load_row(plane_p, S, p0 + r + 1, lane, v);  // overlap with pool
        pool_row<WIN>(buf, outbase + (size_t)(p0 + r) * OUTSZ,
                      x0, lane, sqv, wqv, invqv);
    }
}

__global__ __launch_bounds__(256, 8) void make_cutouts_kernel(
    const float* __restrict__ x,
    const int*   __restrict__ sizes,
    const int*   __restrict__ offy,
    const int*   __restrict__ offx,
    float*       __restrict__ out)
{
    __shared__ float lds[4][2][SLICEF];   // 16640 B -> 8 blocks/CU

    // Bijective XCD chunk swizzle (10752 = 8*1344): XCD k owns planes [3k,3k+3).
    int gid = blockIdx.x;
    int w   = (gid % NXCD) * CHUNKSZ + gid / NXCD;
    int plane = w / (CUTN * NCH);           // 0..23 (= b*CC + c)
    int rest  = w - plane * (CUTN * NCH);
    int i     = rest / NCH;                 // cutout 0..31
    int ch    = rest - i * NCH;             // row-chunk 0..13
    int b     = plane / CC;
    int c     = plane - b * CC;

    // block-uniform per-cutout params -> scalar broadcast
    int S  = sizes[i];
    int y0 = offy[i];
    int x0 = offx[i];
    int tid  = threadIdx.x;
    int wv   = __builtin_amdgcn_readfirstlane(tid >> 6);  // 0..3
    int lane = tid & 63;
    int p0   = ch * RPB + wv * RPW;         // first output row for this wave

    const float* plane_p = x + (size_t)(plane * HH + y0) * WW;
    float* s0 = &lds[wv][0][0];
    float* s1 = &lds[wv][1][0];

    // q-params for this lane's 3-4 output columns (computed once).
    int   sqv[4];
    int   wqv[4];
    float invqv[4];
#pragma unroll
    for (int m = 0; m < 4; ++m) {
        int q = lane + 64 * m;
        int qq = (q < OUTSZ) ? q : 0;       // dummy for inactive (no store)
        int sq = (qq * S) / OUTSZ;
        int wq = ((qq + 1) * S + OUTSZ - 1) / OUTSZ - sq;  // 1..4
        sqv[m] = sq;
        wqv[m] = wq;
        invqv[m] = (wq == 1) ? 1.0f : (wq == 2) ? 0.5f
                 : (wq == 3) ? (1.0f / 3.0f) : 0.25f;
    }

    float* outbase = out + (size_t)((i * BB + b) * CC + c) * OUTSZ * OUTSZ;

    if (S <= 2 * OUTSZ)   // block-uniform: max bin width 3
        run_rows<3>(plane_p, s0, s1, outbase, S, x0, p0, lane, sqv, wqv, invqv);
    else                  // S in (448,512]: max bin width 4
        run_rows<4>(plane_p, s0, s1, outbase, S, x0, p0, lane, sqv, wqv, invqv);
}

extern "C" void kernel_launch(void* const* d_in, const int* in_sizes, int n_in,
                              void* d_out, int out_size, void* d_ws, size_t ws_size,
                              hipStream_t stream) {
    const float* x     = (const float*)d_in[0];
    const int*   sizes = (const int*)d_in[1];
    const int*   offy  = (const int*)d_in[2];
    const int*   offx  = (const int*)d_in[3];
    float* out = (float*)d_out;

    make_cutouts_kernel<<<NBLOCKS, 256, 0, stream>>>(x, sizes, offy, offx, out);
}

// Round 8
// 206.804 us; speedup vs baseline: 1.1966x; 1.1966x over previous
//
#include <hip/hip_runtime.h>

// MakeCutouts: 32 cutouts of (8,3,512,512) fp32 -> adaptive avg pool 224x224.
//
// R11: R10's regression was self-inflicted scratch spill (WRITE 407MB vs
// 150MB output, FETCH 114MB = spill traffic): v[8] prefetch state held live
// across pool + 12-reg q-param arrays under a 64-VGPR cap. Keep the
// barrierless wave-autonomous structure (the real binder is barrier/coupling
// overhead -- all pipes <50% busy in R8/R9/R10), remove the pressure:
//  - NO software prefetch: loads feed the reduce immediately; v[] live range
//    is a few instructions. Latency hiding = TLP (8 blocks/CU x 4 waves =
//    32 waves, the regime that made R6/R7 work).
//  - nontemporal output stores (R9's measured-clean config: FETCH 19MB) so
//    the 154MB write stream doesn't evict the XCD-resident source plane.
//  - double-buffered 520-float wave-private LDS slice (static r&1 index):
//    scheduler can overlap ds_write(row r+1) with pool reads of row r.
//  - zero s_barrier in the kernel; ordering is intra-wave waitcnts.
// Per wave: 4 output rows end-to-end: load wp input rows (2 f32x4/lane) ->
// reduce (v_pk_add_f32) -> ds_write own slice -> pool q=lane+64m via
// cndmask-select window -> NT store. Grid 10752 = 8*1344 bijective XCD
// chunks (XCD k owns planes [3k,3k+3), 1MB plane hot in private L2).

typedef float f32x4 __attribute__((ext_vector_type(4)));

constexpr int OUTSZ = 224;
constexpr int BB    = 8;
constexpr int CC    = 3;
constexpr int HH    = 512;
constexpr int WW    = 512;
constexpr int CUTN  = 32;

constexpr int RPB    = 16;             // output rows per block
constexpr int RPW    = 4;              // rows per wave
constexpr int NCH    = OUTSZ / RPB;    // 14 chunks per (plane,cutout)
constexpr int SLICEF = WW + 8;         // 520 floats (pad for select reads)
constexpr int NPLANE = BB * CC;                    // 24
constexpr int NBLOCKS = NPLANE * CUTN * NCH;       // 10752 = 8 * 1344
constexpr int NXCD   = 8;
constexpr int CHUNKSZ = NBLOCKS / NXCD;            // 1344 = 3 planes worth

__global__ __launch_bounds__(256, 8) void make_cutouts_kernel(
    const float* __restrict__ x,
    const int*   __restrict__ sizes,
    const int*   __restrict__ offy,
    const int*   __restrict__ offx,
    float*       __restrict__ out)
{
    __shared__ float lds[4][2][SLICEF];   // 16.6 KB -> 8 blocks/CU

    // Bijective XCD chunk swizzle (10752 = 8*1344): XCD k owns planes [3k,3k+3).
    int gid = blockIdx.x;
    int w   = (gid % NXCD) * CHUNKSZ + gid / NXCD;
    int plane = w / (CUTN * NCH);           // 0..23 (= b*CC + c)
    int rest  = w - plane * (CUTN * NCH);
    int i     = rest / NCH;                 // cutout 0..31
    int ch    = rest - i * NCH;             // row-chunk 0..13
    int b     = plane / CC;
    int c     = plane - b * CC;

    // block-uniform per-cutout params -> scalar broadcast
    int S  = sizes[i];
    int y0 = offy[i];
    int x0 = offx[i];
    int tid  = threadIdx.x;
    int wv   = __builtin_amdgcn_readfirstlane(tid >> 6);  // 0..3
    int lane = tid & 63;
    int p0   = ch * RPB + wv * RPW;         // first output row for this wave

    const float* plane_p = x + (size_t)(plane * HH + y0) * WW;

    // q-params for this lane's 3-4 output columns, once per wave-chunk.
    // Packed small: sq (int), wq (int), invq (float) per m -> ~9 live regs.
    int   sqv[4];
    int   wqv[4];
    float invqv[4];
#pragma unroll
    for (int m = 0; m < 4; ++m) {
        int q  = lane + 64 * m;
        int qq = (q < OUTSZ) ? q : 0;       // dummy for inactive lanes (no store)
        int sq = (qq * S) / OUTSZ;
        int wq = ((qq + 1) * S + OUTSZ - 1) / OUTSZ - sq;  // 1..4
        sqv[m] = x0 + sq;
        wqv[m] = wq;
        invqv[m] = (wq == 1) ? 1.0f : (wq == 2) ? 0.5f
                 : (wq == 3) ? (1.0f / 3.0f) : 0.25f;
    }

    float* outbase = out + (size_t)((i * BB + b) * CC + c) * OUTSZ * OUTSZ;
    bool win3 = (S <= 2 * OUTSZ);           // block-uniform: max bin width 3

#pragma unroll
    for (int r = 0; r < RPW; ++r) {
        int p  = p0 + r;
        int rs = (p * S) / OUTSZ;                          // scalar magic div
        int wp = ((p + 1) * S + OUTSZ - 1) / OUTSZ - rs;   // 1..4, scalar

        // ---- load wp input rows (2 f32x4 per lane per row) and reduce
        // immediately: v live range is a few instructions (no spill).
        const f32x4* rp = (const f32x4*)(plane_p + (size_t)rs * WW);
        int c0 = lane, c1 = lane + 64;
        f32x4 a0 = rp[c0], a1 = rp[c1];
        if (wp > 1) { f32x4 u0 = rp[c0+128], u1 = rp[c1+128]; a0 += u0; a1 += u1; }
        if (wp > 2) { f32x4 u0 = rp[c0+256], u1 = rp[c1+256]; a0 += u0; a1 += u1; }
        if (wp > 3) { f32x4 u0 = rp[c0+384], u1 = rp[c1+384]; a0 += u0; a1 += u1; }
        float iv = (wp == 1) ? 1.0f : (wp == 2) ? 0.5f
                 : (wp == 3) ? (1.0f / 3.0f) : 0.25f;      // scalar cselect
        a0 *= iv; a1 *= iv;

        // ---- write averaged row to this wave's slice (static r&1 buffer)
        float* buf = &lds[wv][r & 1][0];
        f32x4* t4 = (f32x4*)buf;
        t4[lane]      = a0;
        t4[lane + 64] = a1;

        // ---- pool: lane handles q = lane + 64m (m=3 only for lane<32).
        // cndmask-select window: out-of-window / stale reads are discarded.
        float* outrow = outbase + (size_t)p * OUTSZ;
        float z = 0.0f;
#pragma unroll
        for (int m = 0; m < 4; ++m) {
            if (m == 3 && lane >= 32) break;    // q >= 224
            const float* tr = buf + sqv[m];
            float s = tr[0];                    // adjacent -> ds_read2_b32
            s += (wqv[m] > 1) ? tr[1] : z;
            s += (wqv[m] > 2) ? tr[2] : z;
            if (!win3) s += (wqv[m] > 3) ? tr[3] : z;
            __builtin_nontemporal_store(s * invqv[m], &outrow[lane + 64 * m]);
        }
    }
}

extern "C" void kernel_launch(void* const* d_in, const int* in_sizes, int n_in,
                              void* d_out, int out_size, void* d_ws, size_t ws_size,
                              hipStream_t stream) {
    const float* x     = (const float*)d_in[0];
    const int*   sizes = (const int*)d_in[1];
    const int*   offy  = (const int*)d_in[2];
    const int*   offx  = (const int*)d_in[3];
    float* out = (float*)d_out;

    make_cutouts_kernel<<<NBLOCKS, 256, 0, stream>>>(x, sizes, offy, offx, out);
}

// Round 9
// 203.976 us; speedup vs baseline: 1.2132x; 1.0139x over previous
//
#include <hip/hip_runtime.h>

// MakeCutouts: 32 cutouts of (8,3,512,512) fp32 -> adaptive avg pool 224x224.
//
// R12: R9/R11 proved the barrier was never the binder -- it's the MLP
// enabler (R7's batched loads/ds_reads beat every low-MLP barrierless
// variant). Keep R7 exactly, hide its one exposed latency: the vmcnt(0)
// drain at __syncthreads (last stage loads' L2 latency) and pool's LDS
// latency after it. Split the 8-row tile into halves A/B:
//   issue A loads -> q-params (overlap) -> reduce+write A -> issue B loads
//   -> lgkm-only barrier -> pool A (B loads land underneath) ->
//   reduce+write B (disjoint LDS rows) -> lgkm-only barrier -> pool B
// Barriers wait lgkmcnt(0) ONLY: B's prefetched global loads stay in flight
// across barrier 1 (their wait is the register dep inside reduce+write B).
// VGPR: vB[2][4]=32 live across pool A + ~18 working < 64 cap (no spill --
// R10's lesson). Grid/decode/XCD chunk/LDS identical to R7: 21504 blocks,
// 16.4 KB tile, 8 blocks/CU = 32 waves, stage SALU-scalarized.

typedef float f32x4 __attribute__((ext_vector_type(4)));

constexpr int OUTSZ = 224;
constexpr int BB    = 8;
constexpr int CC    = 3;
constexpr int HH    = 512;
constexpr int WW    = 512;
constexpr int CUTN  = 32;

constexpr int TP     = 8;            // output rows per block (two halves of 4)
constexpr int NBAND  = OUTSZ / TP;   // 28
constexpr int LDSF   = TP * WW + 8;  // 4104 floats = 16416 B
constexpr int NPLANE = BB * CC;                    // 24
constexpr int WPP    = CUTN * NBAND;               // 896
constexpr int NBLOCKS = NPLANE * WPP;              // 21504 = 8 * 2688
constexpr int NXCD   = 8;
constexpr int CHUNK  = NBLOCKS / NXCD;             // 2688 = 3 planes * 896

// Issue global loads for one 4-row half into regs. wv readfirstlane'd ->
// rs/wp/row-base on SALU, loads under uniform s_cbranch. Unloaded v[j][m]
// are stale but never consumed (same wp recomputed at write time).
__device__ __forceinline__ void half_issue(const float* __restrict__ plane_p,
                                           int S, int p0h, int wv, int vo,
                                           f32x4 (&v)[2][4])
{
#pragma unroll
    for (int j = 0; j < 2; ++j) {
        int k  = (wv >> 1) + 2 * j;                        // 0..3 in half
        int p  = p0h + k;
        int rs = (p * S) / OUTSZ;                          // scalar magic div
        int wp = ((p + 1) * S + OUTSZ - 1) / OUTSZ - rs;   // 1..4, scalar
        const f32x4* rp = (const f32x4*)(plane_p + (size_t)rs * WW);
        v[j][0] = rp[vo];
        if (wp > 1) v[j][1] = rp[vo + 128];
        if (wp > 2) v[j][2] = rp[vo + 256];
        if (wp > 3) v[j][3] = rp[vo + 384];
    }
}

// Reduce prefetched rows (v_pk_add_f32), scale by 1/wp, write one averaged
// 512-wide row per output row into tile rows [rowoff, rowoff+4).
__device__ __forceinline__ void half_write(float* __restrict__ tile,
                                           int S, int p0h, int rowoff,
                                           int wv, int vo, f32x4 (&v)[2][4])
{
    f32x4* t4 = (f32x4*)tile;
#pragma unroll
    for (int j = 0; j < 2; ++j) {
        int k  = (wv >> 1) + 2 * j;
        int p  = p0h + k;
        int rs = (p * S) / OUTSZ;
        int wp = ((p + 1) * S + OUTSZ - 1) / OUTSZ - rs;   // 1..4, scalar
        f32x4 a = v[j][0];
        if (wp > 1) a += v[j][1];
        if (wp > 2) a += v[j][2];
        if (wp > 3) a += v[j][3];
        float iv = (wp == 1) ? 1.0f : (wp == 2) ? 0.5f
                 : (wp == 3) ? (1.0f / 3.0f) : 0.25f;      // scalar cselect
        a *= iv;
        t4[(rowoff + k) * 128 + vo] = a;  // adjacent lanes -> ds_write_b128
    }
}

// Pool 4 rows of one half for this thread's fixed column: 3/4-term fma dot
// with weights {invq or 0}. Weight-0 reads hit finite staged data or the
// zeroed end pad, so fma-with-0 is exact.
template <int WIN>
__device__ __forceinline__ void pool_half(const float* __restrict__ tile,
                                          float* __restrict__ outp,
                                          int rowoff, int base,
                                          const float* __restrict__ w)
{
#pragma unroll
    for (int k = 0; k < 4; ++k) {
        const float* tr = tile + (rowoff + k) * WW + base;
        float s = tr[0] * w[0];           // adjacent cols -> ds_read2_b32
        s = fmaf(tr[1], w[1], s);
        s = fmaf(tr[2], w[2], s);
        if (WIN == 4) s = fmaf(tr[3], w[3], s);
        outp[(size_t)k * OUTSZ] = s;
    }
}

// lgkmcnt(0)-only barrier: LDS writes/reads ordered across waves; global
// loads stay in flight (__syncthreads would drain vmcnt(0) -- the exposed
// latency we're deleting).
__device__ __forceinline__ void lgkm_barrier()
{
    asm volatile("s_waitcnt lgkmcnt(0)" ::: "memory");
    __builtin_amdgcn_s_barrier();
}

template <int WIN>
__device__ __forceinline__ void run_block(const float* __restrict__ plane_p,
                                          float* __restrict__ tile,
                                          float* __restrict__ outp,
                                          int S, int p0, int wv, int vo,
                                          int tid, int base,
                                          const float* __restrict__ wt,
                                          f32x4 (&vA)[2][4], f32x4 (&vB)[2][4])
{
    half_write(tile, S, p0, 0, wv, vo, vA);        // reduce+write rows 0-3
    half_issue(plane_p, S, p0 + 4, wv, vo, vB);    // rows 4-7 loads in flight
    lgkm_barrier();                                 // B loads NOT drained
    if (tid < OUTSZ)                                // pool rows 0-3; B lands
        pool_half<WIN>(tile, outp, 0, base, wt);    //   underneath
    half_write(tile, S, p0 + 4, 4, wv, vo, vB);    // disjoint LDS rows: no
    lgkm_barrier();                                 //   barrier needed before
    if (tid < OUTSZ)                                // pool rows 4-7
        pool_half<WIN>(tile, outp + (size_t)4 * OUTSZ, 4, base, wt);
}

__global__ __launch_bounds__(256, 8) void make_cutouts_kernel(
    const float* __restrict__ x,
    const int*   __restrict__ sizes,
    const int*   __restrict__ offy,
    const int*   __restrict__ offx,
    float*       __restrict__ out)
{
    __shared__ float tile[LDSF];   // 16416 B -> 8 blocks/CU

    // Bijective XCD chunk swizzle (21504 = 8*2688): XCD k owns planes
    // [3k, 3k+3); a 1MB plane stays hot in its private 4MB L2.
    int gid = blockIdx.x;
    int w   = (gid % NXCD) * CHUNK + gid / NXCD;
    int plane = w / WPP;          // 0..23  (= b*CC + c)
    int rest  = w - plane * WPP;
    int i     = rest / NBAND;     // cutout 0..31
    int tb    = rest - i * NBAND; // band 0..27
    int b     = plane / CC;
    int c     = plane - b * CC;

    // block-uniform per-cutout params -> scalar broadcast
    int S  = sizes[i];
    int y0 = offy[i];
    int x0 = offx[i];
    int p0 = tb * TP;
    int tid = threadIdx.x;

    const float* plane_p = x + (size_t)(plane * HH + y0) * WW;

    int wv   = __builtin_amdgcn_readfirstlane(tid >> 6);  // 0..3
    int lane = tid & 63;
    int vo   = ((wv & 1) << 6) + lane;    // float4 col index 0..127

    // ---- issue half-A loads FIRST; everything below overlaps their latency
    f32x4 vA[2][4], vB[2][4];
    half_issue(plane_p, S, p0, wv, vo, vA);

    // zero the end pad: row 7's masked reads can touch tile[4096..4098];
    // LDS is stale across blocks and 0*NaN would poison the fma dot.
    if (tid < 8) tile[TP * WW + tid] = 0.0f;

    // pool params (computed once, overlapping A-load latency)
    int sq = (tid * S) / OUTSZ;
    int wq = ((tid + 1) * S + OUTSZ - 1) / OUTSZ - sq;     // 1..4
    float invq = (wq == 1) ? 1.0f : (wq == 2) ? 0.5f
               : (wq == 3) ? (1.0f / 3.0f) : 0.25f;
    float wt[4];
    wt[0] = invq;
    wt[1] = (wq > 1) ? invq : 0.0f;
    wt[2] = (wq > 2) ? invq : 0.0f;
    wt[3] = (wq > 3) ? invq : 0.0f;
    int base = x0 + sq;
    float* outp = out
        + ((size_t)((i * BB + b) * CC + c) * OUTSZ + p0) * OUTSZ + tid;

    if (S <= 2 * OUTSZ)   // block-uniform: max bin width 3
        run_block<3>(plane_p, tile, outp, S, p0, wv, vo, tid, base, wt, vA, vB);
    else                  // S in (448,512]: max bin width 4
        run_block<4>(plane_p, tile, outp, S, p0, wv, vo, tid, base, wt, vA, vB);
}

extern "C" void kernel_launch(void* const* d_in, const int* in_sizes, int n_in,
                              void* d_out, int out_size, void* d_ws, size_t ws_size,
                              hipStream_t stream) {
    const float* x     = (const float*)d_in[0];
    const int*   sizes = (const int*)d_in[1];
    const int*   offy  = (const int*)d_in[2];
    const int*   offx  = (const int*)d_in[3];
    float* out = (float*)d_out;

    make_cutouts_kernel<<<NBLOCKS, 256, 0, stream>>>(x, sizes, offy, offx, out);
}